// Round 1
// baseline (234.781 us; speedup 1.0000x reference)
//
#include <hip/hip_runtime.h>

#define POOL_H 7
#define POOL_W 7
#define SP_SCALE 0.25f
#define SRATIO 2

__global__ __launch_bounds__(256) void roi_align_kernel(
    const float* __restrict__ feat, const float* __restrict__ rois,
    float* __restrict__ out, int N, int C, int H, int W) {
  long long idx = (long long)blockIdx.x * blockDim.x + threadIdx.x;
  long long total = (long long)N * C * POOL_H * POOL_W;
  if (idx >= total) return;

  int pw = (int)(idx % POOL_W);
  int ph = (int)((idx / POOL_W) % POOL_H);
  int c  = (int)((idx / (POOL_W * POOL_H)) % C);
  int n  = (int)(idx / ((long long)POOL_W * POOL_H * C));

  const float* r = rois + (size_t)n * 5;
  int   b  = (int)r[0];
  float sx = r[1] * SP_SCALE - 0.5f;
  float sy = r[2] * SP_SCALE - 0.5f;
  float ex = r[3] * SP_SCALE - 0.5f;
  float ey = r[4] * SP_SCALE - 0.5f;
  float bw = (ex - sx) * (1.0f / POOL_W);
  float bh = (ey - sy) * (1.0f / POOL_H);

  const float* fp = feat + ((size_t)b * C + c) * (size_t)(H * W);

  float acc = 0.0f;
#pragma unroll
  for (int iy = 0; iy < SRATIO; ++iy) {
    float y = sy + ((float)ph + ((float)iy + 0.5f) / SRATIO) * bh;
    bool vy = (y > -1.0f) && (y < (float)H);
    float y0 = fmaxf(y, 0.0f);
    int ylo = (int)floorf(y0);
    int yhi;
    if (ylo >= H - 1) { ylo = H - 1; yhi = H - 1; y0 = (float)ylo; }
    else              { yhi = ylo + 1; }
    float ly = y0 - (float)ylo;

#pragma unroll
    for (int ix = 0; ix < SRATIO; ++ix) {
      float x = sx + ((float)pw + ((float)ix + 0.5f) / SRATIO) * bw;
      bool vx = (x > -1.0f) && (x < (float)W);
      float x0 = fmaxf(x, 0.0f);
      int xlo = (int)floorf(x0);
      int xhi;
      if (xlo >= W - 1) { xlo = W - 1; xhi = W - 1; x0 = (float)xlo; }
      else              { xhi = xlo + 1; }
      float lx = x0 - (float)xlo;

      if (vy && vx) {
        float v00 = fp[(size_t)ylo * W + xlo];
        float v01 = fp[(size_t)ylo * W + xhi];
        float v10 = fp[(size_t)yhi * W + xlo];
        float v11 = fp[(size_t)yhi * W + xhi];
        acc += v00 * (1.0f - ly) * (1.0f - lx)
             + v01 * (1.0f - ly) * lx
             + v10 * ly * (1.0f - lx)
             + v11 * ly * lx;
      }
    }
  }
  out[idx] = acc * (1.0f / (SRATIO * SRATIO));
}

extern "C" void kernel_launch(void* const* d_in, const int* in_sizes, int n_in,
                              void* d_out, int out_size, void* d_ws, size_t ws_size,
                              hipStream_t stream) {
  const float* feat = (const float*)d_in[0];
  const float* rois = (const float*)d_in[1];
  float* out = (float*)d_out;

  const int B = 2, C = 256, H = 200, W = 336;
  const int N = in_sizes[1] / 5;  // rois is (N, 5)
  (void)B; (void)n_in; (void)d_ws; (void)ws_size; (void)out_size;

  long long total = (long long)N * C * POOL_H * POOL_W;
  int block = 256;
  long long grid = (total + block - 1) / block;
  roi_align_kernel<<<(int)grid, block, 0, stream>>>(feat, rois, out, N, C, H, W);
}